// Round 1
// baseline (778.093 us; speedup 1.0000x reference)
//
#include <hip/hip_runtime.h>
#include <hip/hip_fp16.h>

#define TSTEPS 276
#define NBATCH 32768
#define KDIM   4416   // 276*16
#define NPAD   320    // Wfc rows padded to 2*160
#define NOUT   276
#define GBM    64     // gemm block M
#define GBN    320    // gemm block N (full)
#define NCHUNK 138    // KDIM / 32

typedef _Float16 half8 __attribute__((ext_vector_type(8)));
typedef float    f32x4 __attribute__((ext_vector_type(4)));

__device__ __forceinline__ float fast_sigmoid(float x) {
    float e = __builtin_amdgcn_exp2f(-1.4426950408889634f * x);
    return __builtin_amdgcn_rcpf(1.0f + e);
}
__device__ __forceinline__ float fast_tanh(float x) {
    float e = __builtin_amdgcn_exp2f(2.885390081777927f * x);
    return 1.0f - 2.0f * __builtin_amdgcn_rcpf(1.0f + e);
}

__device__ __forceinline__ void async_copy16(const void* g, void* l) {
    __builtin_amdgcn_global_load_lds(
        (const __attribute__((address_space(1))) void*)g,
        (__attribute__((address_space(3))) void*)l, 16, 0, 0);
}

// broadcast h from lane (lane&0x18)|j within each 8-lane group (BitMode swizzle,
// immediate pattern: and=0x18, or=j, xor=0 -> offset=(j<<5)|0x18). Groups are
// 8-aligned so they never cross the 32-lane swizzle half.
#define HSWZ(dst, hb, j) dst = __int_as_float(__builtin_amdgcn_ds_swizzle(hb, ((j) << 5) | 0x18))

// ---------------- Kernel 1: bidirectional LSTM (unchanged this round) -------
// VALU-issue-bound (VALUBusy 95%). Next-round candidate: pack 2 batch rows per
// lane as float2 + v_pk_fma_f32 to halve FMA issue per batch element.
__global__ __launch_bounds__(256, 4) void lstm_kernel(
    const float* __restrict__ x,
    const float* __restrict__ Wih_f, const float* __restrict__ Whh_f,
    const float* __restrict__ bih_f, const float* __restrict__ bhh_f,
    const float* __restrict__ Wih_b, const float* __restrict__ Whh_b,
    const float* __restrict__ bih_b, const float* __restrict__ bhh_b,
    int row0, _Float16* __restrict__ Hout)
{
    const int tid = threadIdx.x;
    const int k   = tid & 7;
    const int rd  = blockIdx.x * 32 + (tid >> 3);
    const int bl  = rd >> 1;
    const int dir = rd & 1;
    const int bg  = row0 + bl;

    const float* Wih = dir ? Wih_b : Wih_f;
    const float* Whh = dir ? Whh_b : Whh_f;
    const float* bih = dir ? bih_b : bih_f;
    const float* bhh = dir ? bhh_b : bhh_f;

    float Wk[4][8], Wi0[4], Wi1[4], bs[4];
    #pragma unroll
    for (int g = 0; g < 4; ++g) {
        int row = g * 8 + k;                       // PyTorch gate order i,f,g,o
        #pragma unroll
        for (int j = 0; j < 8; ++j) Wk[g][j] = Whh[row * 8 + j];
        Wi0[g] = Wih[row * 2 + 0];
        Wi1[g] = Wih[row * 2 + 1];
        bs[g]  = bih[row] + bhh[row];
    }
    // pin every weight in an ArchVGPR: forbids rematerialization/reload
    #pragma unroll
    for (int g = 0; g < 4; ++g) {
        #pragma unroll
        for (int j = 0; j < 8; ++j) asm volatile("" : "+v"(Wk[g][j]));
        asm volatile("" : "+v"(Wi0[g]));
        asm volatile("" : "+v"(Wi1[g]));
        asm volatile("" : "+v"(bs[g]));
    }

    const float2* __restrict__ xrow = (const float2*)(x + (size_t)bg * (TSTEPS * 2));
    _Float16* __restrict__ hrow = Hout + (size_t)bl * KDIM + dir * 8 + k;

    float h = 0.0f, c = 0.0f;
    float2 xv = xrow[dir ? (TSTEPS - 1) : 0];
    for (int s = 0; s < TSTEPS; ++s) {
        const int sn = (s + 1 < TSTEPS) ? (s + 1) : s;
        const float2 xv_n = xrow[dir ? (TSTEPS - 1 - sn) : sn];   // prefetch

        const int hb = __float_as_int(h);
        float hv[8];
        HSWZ(hv[0], hb, 0); HSWZ(hv[1], hb, 1); HSWZ(hv[2], hb, 2); HSWZ(hv[3], hb, 3);
        HSWZ(hv[4], hb, 4); HSWZ(hv[5], hb, 5); HSWZ(hv[6], hb, 6); HSWZ(hv[7], hb, 7);

        float a[4];
        #pragma unroll
        for (int g = 0; g < 4; ++g) {
            float acc = fmaf(xv.x, Wi0[g], bs[g]);
            acc = fmaf(xv.y, Wi1[g], acc);
            #pragma unroll
            for (int j = 0; j < 8; ++j) acc = fmaf(Wk[g][j], hv[j], acc);
            a[g] = acc;
        }
        const float ig = fast_sigmoid(a[0]);
        const float fg = fast_sigmoid(a[1]);
        const float gg = fast_tanh(a[2]);
        const float og = fast_sigmoid(a[3]);
        c = fmaf(fg, c, ig * gg);
        h = og * fast_tanh(c);

        hrow[s * 16] = (_Float16)h;                // time-of-step layout (bwd reversed)
        xv = xv_n;
    }
}

// ---------------- Kernel 2: Wfc fp32 -> fp16 with K-permutation -------------
// H k-layout: p = s*16 + d*8 + j holds fwd h[t=s][j] (d=0) or bwd h[t=275-s][j]
// (d=1). So W2[n][p] = Wfc[n][p] for d=0, Wfc[n][(275-s)*16 + 8 + j] for d=1.
__global__ __launch_bounds__(256) void conv_kernel(const float* __restrict__ Wfc,
                                                   _Float16* __restrict__ W2)
{
    int i = blockIdx.x * 256 + threadIdx.x;
    if (i < NPAD * KDIM) {
        int n = i / KDIM, p = i - n * KDIM;
        _Float16 v = (_Float16)0.0f;
        if (n < NOUT) {
            int s = p >> 4, r = p & 15;
            int src = (r < 8) ? p : ((TSTEPS - 1 - s) * 16 + r);
            v = (_Float16)Wfc[n * KDIM + src];
        }
        W2[i] = v;
    }
}

// ---------------- Kernel 3: out[rows,276] = H[rows,4416] * W2^T + bfc -------
// Rewritten: 3-deep counted-vmcnt pipeline + XOR-swizzled LDS.
//  (a) Bank conflicts: row-major 64B LDS rows put fragment-read lanes 0..15 at
//      a 64B stride -> ~8-way conflict. Fix (T2 + rule #21): keep the
//      global_load_lds DEST linear, permute the global SOURCE 16B chunk by
//      chunk ^ ((row>>1)&3), and apply the same involution on the ds_read
//      address. Read lanes then cover all 8 bank-start slots exactly 2x
//      (2-way aliasing = free).
//  (b) Latency: __syncthreads drained vmcnt(0) every K-step, exposing ~900cy
//      HBM latency per chunk with only 2 blocks/CU. Fix (T3/T4): 3 LDS
//      buffers (72KB -> still 2 blocks/CU), raw s_barrier, counted
//      s_waitcnt vmcnt(12) so 2 chunks (12 loads) stay in flight across
//      barriers; drain 12/6/0 only in the peeled tail. Per iter: wait chunk k
//      -> barrier -> 12 ds_read_b128 to regs -> lgkmcnt(0) -> barrier ->
//      restage buffer with chunk k+3 -> 20 MFMAs overlap the staging.
__global__ __launch_bounds__(256, 2) void gemm_kernel(
    const _Float16* __restrict__ H, const _Float16* __restrict__ W2,
    const float* __restrict__ bfc, float* __restrict__ out)
{
    __shared__ char smem[3][(GBM + GBN) * 64];     // per buf: A 4KB @0, B 20KB @4096

    const int tid  = threadIdx.x;
    const int lane = tid & 63;
    const int w    = tid >> 6;
    const int wm   = w >> 1;                       // 32-row half
    const int wn   = w & 1;                        // 160-col half
    const int m0   = blockIdx.x * GBM;
    const int l15  = lane & 15;
    const int l4   = lane >> 4;
    const int sel  = (l15 >> 1) & 3;               // row-derived swizzle selector
    const int cq   = (l4 ^ sel) << 4;              // swizzled 16B chunk offset in 64B row

    f32x4 acc[2][10] = {};

    // stage one 32-k chunk (24 KB = 24 slots of 1KB; 6 slots per wave).
    // LDS dest is linear (hardware requirement); the SOURCE chunk within each
    // 64B row is permuted by the involution chunk ^ ((row>>1)&3).
    auto stage = [&](int k0, char* buf) {
        #pragma unroll
        for (int i = 0; i < 6; ++i) {
            const int j = w + 4 * i;               // 0..23, wave-uniform
            const int f = (j << 10) + lane * 16;
            const char* g;
            if (j < 4) {                            // A region (4 KB): row = f>>6
                const int soff = ((((f >> 4) & 3) ^ ((f >> 7) & 3)) << 4);
                g = (const char*)(H + (size_t)(m0 + (f >> 6)) * KDIM + k0) + soff;
            } else {                                // B region (20 KB)
                const int fb = f - 4096;
                const int soff = ((((fb >> 4) & 3) ^ ((fb >> 7) & 3)) << 4);
                g = (const char*)(W2 + (size_t)(fb >> 6) * KDIM + k0) + soff;
            }
            async_copy16(g, buf + (j << 10));
        }
    };

    half8 af[2], bf[10];
    auto load_frags = [&](const char* buf) {
        const char* A  = buf;
        const char* Bb = buf + 4096;
        #pragma unroll
        for (int mi = 0; mi < 2; ++mi)
            af[mi] = *(const half8*)(A + (wm * 32 + mi * 16 + l15) * 64 + cq);
        #pragma unroll
        for (int ni = 0; ni < 10; ++ni)
            bf[ni] = *(const half8*)(Bb + (wn * 160 + ni * 16 + l15) * 64 + cq);
    };
    auto do_mfma = [&]() {
        #pragma unroll
        for (int ni = 0; ni < 10; ++ni) {
            #pragma unroll
            for (int mi = 0; mi < 2; ++mi)
                acc[mi][ni] = __builtin_amdgcn_mfma_f32_16x16x32_f16(af[mi], bf[ni], acc[mi][ni], 0, 0, 0);
        }
    };

    #define WAITVM(N) asm volatile("s_waitcnt vmcnt(" #N ")" ::: "memory")
    #define WAITLG()  asm volatile("s_waitcnt lgkmcnt(0)" ::: "memory")

    // prologue: fill the 3-deep pipe (18 loads in flight per wave)
    stage(0,  smem[0]);
    stage(32, smem[1]);
    stage(64, smem[2]);

    // main loop: chunks 0..134 (135 = 45*3), always 2 chunks kept in flight
    #pragma unroll 1
    for (int ck = 0; ck < NCHUNK - 3; ck += 3) {
        #pragma unroll
        for (int u = 0; u < 3; ++u) {
            WAITVM(12);                            // my chunk (ck+u) loads done
            __builtin_amdgcn_s_barrier();          // everyone's chunk (ck+u) done
            load_frags(smem[u]);                   // 12x ds_read_b128 -> regs
            WAITLG();                              // reads committed before overwrite
            __builtin_amdgcn_s_barrier();          // all waves done reading buf u
            stage((ck + u + 3) * 32, smem[u]);     // refill with chunk ck+u+3
            __builtin_amdgcn_sched_barrier(0);     // keep stage issued before MFMAs
            do_mfma();                             // 20 MFMAs hide staging latency
        }
    }
    // tail: chunks 135,136,137 — drain 12 -> 6 -> 0
    WAITVM(12); __builtin_amdgcn_s_barrier(); load_frags(smem[0]); do_mfma();
    WAITVM(6);  __builtin_amdgcn_s_barrier(); load_frags(smem[1]); do_mfma();
    WAITVM(0);  __builtin_amdgcn_s_barrier(); load_frags(smem[2]); do_mfma();

    #undef WAITVM
    #undef WAITLG

    // C layout (16x16): col = lane&15, row = (lane>>4)*4 + reg
    #pragma unroll
    for (int ni = 0; ni < 10; ++ni) {
        const int n = wn * 160 + ni * 16 + l15;
        if (n < NOUT) {
            const float bv = bfc[n];
            #pragma unroll
            for (int mi = 0; mi < 2; ++mi) {
                const int mbase = m0 + wm * 32 + mi * 16 + l4 * 4;
                #pragma unroll
                for (int g = 0; g < 4; ++g)
                    out[(size_t)(mbase + g) * NOUT + n] = acc[mi][ni][g] + bv;
            }
        }
    }
}

extern "C" void kernel_launch(void* const* d_in, const int* in_sizes, int n_in,
                              void* d_out, int out_size, void* d_ws, size_t ws_size,
                              hipStream_t stream) {
    const float* x     = (const float*)d_in[0];
    const float* Wih_f = (const float*)d_in[1];
    const float* Whh_f = (const float*)d_in[2];
    const float* bih_f = (const float*)d_in[3];
    const float* bhh_f = (const float*)d_in[4];
    const float* Wih_b = (const float*)d_in[5];
    const float* Whh_b = (const float*)d_in[6];
    const float* bih_b = (const float*)d_in[7];
    const float* bhh_b = (const float*)d_in[8];
    const float* Wfc   = (const float*)d_in[9];
    const float* bfc   = (const float*)d_in[10];
    float* out = (float*)d_out;

    // Workspace layout: [W2: NPAD*KDIM fp16][H chunk: chunk*KDIM fp16]
    _Float16* W2 = (_Float16*)d_ws;
    size_t h_off = ((size_t)NPAD * KDIM * 2 + 255) & ~(size_t)255;
    size_t avail = (ws_size > h_off) ? (ws_size - h_off) : 0;
    long maxrows = (long)(avail / ((size_t)KDIM * 2));
    int chunk = (int)((maxrows / 128) * 128);
    if (chunk > NBATCH) chunk = NBATCH;
    if (chunk < 128)    chunk = 128;
    _Float16* Hc = (_Float16*)((char*)d_ws + h_off);

    conv_kernel<<<(NPAD * KDIM + 255) / 256, 256, 0, stream>>>(Wfc, W2);

    for (int r0 = 0; r0 < NBATCH; r0 += chunk) {
        int rows = NBATCH - r0; if (rows > chunk) rows = chunk;
        lstm_kernel<<<rows / 16, 256, 0, stream>>>(x, Wih_f, Whh_f, bih_f, bhh_f,
                                                   Wih_b, Whh_b, bih_b, bhh_b,
                                                   r0, Hc);
        gemm_kernel<<<rows / 64, 256, 0, stream>>>(Hc, W2, bfc,
                                                   out + (size_t)r0 * NOUT);
    }
}

// Round 2
// 698.150 us; speedup vs baseline: 1.1145x; 1.1145x over previous
//
#include <hip/hip_runtime.h>
#include <hip/hip_fp16.h>

#define TSTEPS 276
#define NBATCH 32768
#define KDIM   4416   // 276*16
#define NPAD   320    // Wfc rows padded to 2*160
#define NOUT   276
#define GBM    64     // gemm block M
#define GBN    320    // gemm block N (full)
#define NCHUNK 138    // KDIM / 32
#define TILE_ELE 2048 // 64 rows * 32 k per (nb,nk) tile
#define ROWBLK_ELE (138 * 2048)  // elements per 64-row block of H (138 k-tiles)

typedef _Float16 half8 __attribute__((ext_vector_type(8)));
typedef float    f32x4 __attribute__((ext_vector_type(4)));

__device__ __forceinline__ float fast_sigmoid(float x) {
    float e = __builtin_amdgcn_exp2f(-1.4426950408889634f * x);
    return __builtin_amdgcn_rcpf(1.0f + e);
}
__device__ __forceinline__ float fast_tanh(float x) {
    float e = __builtin_amdgcn_exp2f(2.885390081777927f * x);
    return 1.0f - 2.0f * __builtin_amdgcn_rcpf(1.0f + e);
}

__device__ __forceinline__ void async_copy16(const void* g, void* l) {
    __builtin_amdgcn_global_load_lds(
        (const __attribute__((address_space(1))) void*)g,
        (__attribute__((address_space(3))) void*)l, 16, 0, 0);
}

// broadcast h from lane (lane&0x18)|j within each 8-lane group (BitMode swizzle)
#define HSWZ(dst, hb, j) dst = __int_as_float(__builtin_amdgcn_ds_swizzle(hb, ((j) << 5) | 0x18))

// ---------------- Kernel 1: bidirectional LSTM ----------------
// THIS ROUND: H is written in gemm-native tiles Ht[b/64][k/32][64][32] (fp16).
// Old layout wrote 32B fragments at 8832B stride -> ~0.82 TB/s write ceiling
// (fine-grained HBM scatter). In tile layout, iteration s (both dirs - storage
// index == iteration index) fills contiguous per-row 16B pieces of the SAME
// k-tile across 64 adjacent batch rows (2 adjacent blocks, ~same wall time)
// -> full 128B-line write combining. Element at logical (row bl, p) with
// p = s*16 + dir*8 + j lives at ((bl>>6)*138 + (p>>5))*2048 + (bl&63)*32 + (p&31).
__global__ __launch_bounds__(256, 4) void lstm_kernel(
    const float* __restrict__ x,
    const float* __restrict__ Wih_f, const float* __restrict__ Whh_f,
    const float* __restrict__ bih_f, const float* __restrict__ bhh_f,
    const float* __restrict__ Wih_b, const float* __restrict__ Whh_b,
    const float* __restrict__ bih_b, const float* __restrict__ bhh_b,
    int row0, _Float16* __restrict__ Hout)
{
    const int tid = threadIdx.x;
    const int k   = tid & 7;
    const int rd  = blockIdx.x * 32 + (tid >> 3);
    const int bl  = rd >> 1;
    const int dir = rd & 1;
    const int bg  = row0 + bl;

    const float* Wih = dir ? Wih_b : Wih_f;
    const float* Whh = dir ? Whh_b : Whh_f;
    const float* bih = dir ? bih_b : bih_f;
    const float* bhh = dir ? bhh_b : bhh_f;

    float Wk[4][8], Wi0[4], Wi1[4], bs[4];
    #pragma unroll
    for (int g = 0; g < 4; ++g) {
        int row = g * 8 + k;                       // PyTorch gate order i,f,g,o
        #pragma unroll
        for (int j = 0; j < 8; ++j) Wk[g][j] = Whh[row * 8 + j];
        Wi0[g] = Wih[row * 2 + 0];
        Wi1[g] = Wih[row * 2 + 1];
        bs[g]  = bih[row] + bhh[row];
    }
    // pin every weight in an ArchVGPR: forbids rematerialization/reload
    #pragma unroll
    for (int g = 0; g < 4; ++g) {
        #pragma unroll
        for (int j = 0; j < 8; ++j) asm volatile("" : "+v"(Wk[g][j]));
        asm volatile("" : "+v"(Wi0[g]));
        asm volatile("" : "+v"(Wi1[g]));
        asm volatile("" : "+v"(bs[g]));
    }

    const float2* __restrict__ xrow = (const float2*)(x + (size_t)bg * (TSTEPS * 2));
    // tiled store base: nb = bl>>6, r = bl&63; step s writes hp[(s&1)*16],
    // advancing one k-tile (2048 ele) after each odd s.
    _Float16* __restrict__ hp = Hout + (size_t)(bl >> 6) * ROWBLK_ELE
                                      + (bl & 63) * 32 + dir * 8 + k;

    float h = 0.0f, c = 0.0f;
    float2 xv = xrow[dir ? (TSTEPS - 1) : 0];
    #pragma unroll 2
    for (int s = 0; s < TSTEPS; ++s) {
        const int sn = (s + 1 < TSTEPS) ? (s + 1) : s;
        const float2 xv_n = xrow[dir ? (TSTEPS - 1 - sn) : sn];   // prefetch

        const int hb = __float_as_int(h);
        float hv[8];
        HSWZ(hv[0], hb, 0); HSWZ(hv[1], hb, 1); HSWZ(hv[2], hb, 2); HSWZ(hv[3], hb, 3);
        HSWZ(hv[4], hb, 4); HSWZ(hv[5], hb, 5); HSWZ(hv[6], hb, 6); HSWZ(hv[7], hb, 7);

        float a[4];
        #pragma unroll
        for (int g = 0; g < 4; ++g) {
            float acc = fmaf(xv.x, Wi0[g], bs[g]);
            acc = fmaf(xv.y, Wi1[g], acc);
            #pragma unroll
            for (int j = 0; j < 8; ++j) acc = fmaf(Wk[g][j], hv[j], acc);
            a[g] = acc;
        }
        const float ig = fast_sigmoid(a[0]);
        const float fg = fast_sigmoid(a[1]);
        const float gg = fast_tanh(a[2]);
        const float og = fast_sigmoid(a[3]);
        c = fmaf(fg, c, ig * gg);
        h = og * fast_tanh(c);

        hp[(s & 1) << 4] = (_Float16)h;            // kc = (s&1)*16 + dir*8 + j
        hp += (size_t)((s & 1) << 11);             // +2048 ele after odd steps
        xv = xv_n;
    }
}

// ---------------- Kernel 2: Wfc fp32 -> fp16 with K-permutation -------------
// (unchanged; B stays row-major [320][4416], L2-resident in the gemm)
__global__ __launch_bounds__(256) void conv_kernel(const float* __restrict__ Wfc,
                                                   _Float16* __restrict__ W2)
{
    int i = blockIdx.x * 256 + threadIdx.x;
    if (i < NPAD * KDIM) {
        int n = i / KDIM, p = i - n * KDIM;
        _Float16 v = (_Float16)0.0f;
        if (n < NOUT) {
            int s = p >> 4, r = p & 15;
            int src = (r < 8) ? p : ((TSTEPS - 1 - s) * 16 + r);
            v = (_Float16)Wfc[n * KDIM + src];
        }
        W2[i] = v;
    }
}

// ---------------- Kernel 3: out[rows,276] = H[rows,4416] * W2^T + bfc -------
// Structure identical to R1 (3-deep counted-vmcnt pipeline, XOR-swizzled LDS).
// THIS ROUND: A is read from the tiled H layout -> each chunk-stage is one
// CONTIGUOUS 4KB block (4 consecutive 1KB wave loads) instead of 64 rows x
// 64B at 8832B stride. The LDS image is byte-identical to R1 (source permute
// applied within the tile), so load_frags / swizzle / MFMA are untouched.
__global__ __launch_bounds__(256, 2) void gemm_kernel(
    const _Float16* __restrict__ H, const _Float16* __restrict__ W2,
    const float* __restrict__ bfc, float* __restrict__ out)
{
    __shared__ char smem[3][(GBM + GBN) * 64];     // per buf: A 4KB @0, B 20KB @4096

    const int tid  = threadIdx.x;
    const int lane = tid & 63;
    const int w    = tid >> 6;
    const int wm   = w >> 1;                       // 32-row half
    const int wn   = w & 1;                        // 160-col half
    const int m0   = blockIdx.x * GBM;
    const int l15  = lane & 15;
    const int l4   = lane >> 4;
    const int sel  = (l15 >> 1) & 3;               // row-derived swizzle selector
    const int cq   = (l4 ^ sel) << 4;              // swizzled 16B chunk offset in 64B row

    // base of this block's 64-row tile stripe in the tiled H layout
    const char* __restrict__ Htile = (const char*)(H + (size_t)(m0 >> 6) * ROWBLK_ELE);

    f32x4 acc[2][10] = {};

    // stage one 32-k chunk (24 KB = 24 slots of 1KB; 6 slots per wave).
    // LDS dest linear (HW requirement); source 16B chunk within each 64B row
    // permuted by the involution chunk ^ ((row>>1)&3)  (rule #21).
    auto stage = [&](int k0, char* buf) {
        #pragma unroll
        for (int i = 0; i < 6; ++i) {
            const int j = w + 4 * i;               // 0..23, wave-uniform
            const int f = (j << 10) + lane * 16;
            const char* g;
            if (j < 4) {                            // A region: contiguous 4KB tile
                const int soff = ((((f >> 4) & 3) ^ ((f >> 7) & 3)) << 4);
                g = Htile + (size_t)(k0 >> 5) * 4096 + (f & ~63) + soff;
            } else {                                // B region (20 KB), row-major W2
                const int fb = f - 4096;
                const int soff = ((((fb >> 4) & 3) ^ ((fb >> 7) & 3)) << 4);
                g = (const char*)(W2 + (size_t)(fb >> 6) * KDIM + k0) + soff;
            }
            async_copy16(g, buf + (j << 10));
        }
    };

    half8 af[2], bf[10];
    auto load_frags = [&](const char* buf) {
        const char* A  = buf;
        const char* Bb = buf + 4096;
        #pragma unroll
        for (int mi = 0; mi < 2; ++mi)
            af[mi] = *(const half8*)(A + (wm * 32 + mi * 16 + l15) * 64 + cq);
        #pragma unroll
        for (int ni = 0; ni < 10; ++ni)
            bf[ni] = *(const half8*)(Bb + (wn * 160 + ni * 16 + l15) * 64 + cq);
    };
    auto do_mfma = [&]() {
        #pragma unroll
        for (int ni = 0; ni < 10; ++ni) {
            #pragma unroll
            for (int mi = 0; mi < 2; ++mi)
                acc[mi][ni] = __builtin_amdgcn_mfma_f32_16x16x32_f16(af[mi], bf[ni], acc[mi][ni], 0, 0, 0);
        }
    };

    #define WAITVM(N) asm volatile("s_waitcnt vmcnt(" #N ")" ::: "memory")
    #define WAITLG()  asm volatile("s_waitcnt lgkmcnt(0)" ::: "memory")

    // prologue: fill the 3-deep pipe (18 loads in flight per wave)
    stage(0,  smem[0]);
    stage(32, smem[1]);
    stage(64, smem[2]);

    #pragma unroll 1
    for (int ck = 0; ck < NCHUNK - 3; ck += 3) {
        #pragma unroll
        for (int u = 0; u < 3; ++u) {
            WAITVM(12);                            // my chunk (ck+u) loads done
            __builtin_amdgcn_s_barrier();          // everyone's chunk (ck+u) done
            load_frags(smem[u]);                   // 12x ds_read_b128 -> regs
            WAITLG();                              // reads committed before overwrite
            __builtin_amdgcn_s_barrier();          // all waves done reading buf u
            stage((ck + u + 3) * 32, smem[u]);     // refill with chunk ck+u+3
            __builtin_amdgcn_sched_barrier(0);     // keep stage issued before MFMAs
            do_mfma();                             // 20 MFMAs hide staging latency
        }
    }
    // tail: chunks 135,136,137 — drain 12 -> 6 -> 0
    WAITVM(12); __builtin_amdgcn_s_barrier(); load_frags(smem[0]); do_mfma();
    WAITVM(6);  __builtin_amdgcn_s_barrier(); load_frags(smem[1]); do_mfma();
    WAITVM(0);  __builtin_amdgcn_s_barrier(); load_frags(smem[2]); do_mfma();

    #undef WAITVM
    #undef WAITLG

    // C layout (16x16): col = lane&15, row = (lane>>4)*4 + reg
    #pragma unroll
    for (int ni = 0; ni < 10; ++ni) {
        const int n = wn * 160 + ni * 16 + l15;
        if (n < NOUT) {
            const float bv = bfc[n];
            #pragma unroll
            for (int mi = 0; mi < 2; ++mi) {
                const int mbase = m0 + wm * 32 + mi * 16 + l4 * 4;
                #pragma unroll
                for (int g = 0; g < 4; ++g)
                    out[(size_t)(mbase + g) * NOUT + n] = acc[mi][ni][g] + bv;
            }
        }
    }
}

extern "C" void kernel_launch(void* const* d_in, const int* in_sizes, int n_in,
                              void* d_out, int out_size, void* d_ws, size_t ws_size,
                              hipStream_t stream) {
    const float* x     = (const float*)d_in[0];
    const float* Wih_f = (const float*)d_in[1];
    const float* Whh_f = (const float*)d_in[2];
    const float* bih_f = (const float*)d_in[3];
    const float* bhh_f = (const float*)d_in[4];
    const float* Wih_b = (const float*)d_in[5];
    const float* Whh_b = (const float*)d_in[6];
    const float* bih_b = (const float*)d_in[7];
    const float* bhh_b = (const float*)d_in[8];
    const float* Wfc   = (const float*)d_in[9];
    const float* bfc   = (const float*)d_in[10];
    float* out = (float*)d_out;

    // Workspace layout: [W2: NPAD*KDIM fp16][H chunk (tiled): chunk*KDIM fp16]
    _Float16* W2 = (_Float16*)d_ws;
    size_t h_off = ((size_t)NPAD * KDIM * 2 + 255) & ~(size_t)255;
    size_t avail = (ws_size > h_off) ? (ws_size - h_off) : 0;
    long maxrows = (long)(avail / ((size_t)KDIM * 2));
    int chunk = (int)((maxrows / 128) * 128);
    if (chunk > NBATCH) chunk = NBATCH;
    if (chunk < 128)    chunk = 128;
    _Float16* Hc = (_Float16*)((char*)d_ws + h_off);

    conv_kernel<<<(NPAD * KDIM + 255) / 256, 256, 0, stream>>>(Wfc, W2);

    for (int r0 = 0; r0 < NBATCH; r0 += chunk) {
        int rows = NBATCH - r0; if (rows > chunk) rows = chunk;
        lstm_kernel<<<rows / 16, 256, 0, stream>>>(x, Wih_f, Whh_f, bih_f, bhh_f,
                                                   Wih_b, Whh_b, bih_b, bhh_b,
                                                   r0, Hc);
        gemm_kernel<<<rows / 64, 256, 0, stream>>>(Hc, W2, bfc,
                                                   out + (size_t)r0 * NOUT);
    }
}

// Round 4
// 643.718 us; speedup vs baseline: 1.2087x; 1.0846x over previous
//
#include <hip/hip_runtime.h>
#include <hip/hip_fp16.h>

#define TSTEPS 276
#define NBATCH 32768
#define KDIM   4416   // 276*16
#define NPAD   320    // Wfc rows padded to 2*160
#define NOUT   276
#define GBM    64     // gemm block M
#define GBN    320    // gemm block N (full)
#define NCHUNK 138    // KDIM / 32
#define ROWBLK_ELE (138 * 2048)  // elements per 64-row block of H (138 k-tiles)
#define BTILE_ELE  (320 * 32)    // elements per k-tile of W2t (10240)

typedef _Float16 half8 __attribute__((ext_vector_type(8)));
typedef float    f32x4 __attribute__((ext_vector_type(4)));

__device__ __forceinline__ float fast_sigmoid(float x) {
    float e = __builtin_amdgcn_exp2f(-1.4426950408889634f * x);
    return __builtin_amdgcn_rcpf(1.0f + e);
}
__device__ __forceinline__ float fast_tanh(float x) {
    float e = __builtin_amdgcn_exp2f(2.885390081777927f * x);
    return 1.0f - 2.0f * __builtin_amdgcn_rcpf(1.0f + e);
}

__device__ __forceinline__ void async_copy16(const void* g, void* l) {
    __builtin_amdgcn_global_load_lds(
        (const __attribute__((address_space(1))) void*)g,
        (__attribute__((address_space(3))) void*)l, 16, 0, 0);
}

// broadcast h from lane (lane&0x18)|j within each 8-lane group (BitMode swizzle)
#define HSWZ(dst, hb, j) dst = __int_as_float(__builtin_amdgcn_ds_swizzle(hb, ((j) << 5) | 0x18))

// ---------------- Kernel 1: bidirectional LSTM (unchanged) ----------------
// Issue-bound (VALUBusy ~100%). H written in gemm-native tiles
// Ht[b/64][k/32][64][32] fp16 (R2 change, kept).
__global__ __launch_bounds__(256, 4) void lstm_kernel(
    const float* __restrict__ x,
    const float* __restrict__ Wih_f, const float* __restrict__ Whh_f,
    const float* __restrict__ bih_f, const float* __restrict__ bhh_f,
    const float* __restrict__ Wih_b, const float* __restrict__ Whh_b,
    const float* __restrict__ bih_b, const float* __restrict__ bhh_b,
    int row0, _Float16* __restrict__ Hout)
{
    const int tid = threadIdx.x;
    const int k   = tid & 7;
    const int rd  = blockIdx.x * 32 + (tid >> 3);
    const int bl  = rd >> 1;
    const int dir = rd & 1;
    const int bg  = row0 + bl;

    const float* Wih = dir ? Wih_b : Wih_f;
    const float* Whh = dir ? Whh_b : Whh_f;
    const float* bih = dir ? bih_b : bih_f;
    const float* bhh = dir ? bhh_b : bhh_f;

    float Wk[4][8], Wi0[4], Wi1[4], bs[4];
    #pragma unroll
    for (int g = 0; g < 4; ++g) {
        int row = g * 8 + k;                       // PyTorch gate order i,f,g,o
        #pragma unroll
        for (int j = 0; j < 8; ++j) Wk[g][j] = Whh[row * 8 + j];
        Wi0[g] = Wih[row * 2 + 0];
        Wi1[g] = Wih[row * 2 + 1];
        bs[g]  = bih[row] + bhh[row];
    }
    // pin every weight in an ArchVGPR: forbids rematerialization/reload
    #pragma unroll
    for (int g = 0; g < 4; ++g) {
        #pragma unroll
        for (int j = 0; j < 8; ++j) asm volatile("" : "+v"(Wk[g][j]));
        asm volatile("" : "+v"(Wi0[g]));
        asm volatile("" : "+v"(Wi1[g]));
        asm volatile("" : "+v"(bs[g]));
    }

    const float2* __restrict__ xrow = (const float2*)(x + (size_t)bg * (TSTEPS * 2));
    // tiled store base: nb = bl>>6, r = bl&63; step s writes hp[(s&1)*16],
    // advancing one k-tile (2048 ele) after each odd s.
    _Float16* __restrict__ hp = Hout + (size_t)(bl >> 6) * ROWBLK_ELE
                                      + (bl & 63) * 32 + dir * 8 + k;

    float h = 0.0f, c = 0.0f;
    float2 xv = xrow[dir ? (TSTEPS - 1) : 0];
    #pragma unroll 2
    for (int s = 0; s < TSTEPS; ++s) {
        const int sn = (s + 1 < TSTEPS) ? (s + 1) : s;
        const float2 xv_n = xrow[dir ? (TSTEPS - 1 - sn) : sn];   // prefetch

        const int hb = __float_as_int(h);
        float hv[8];
        HSWZ(hv[0], hb, 0); HSWZ(hv[1], hb, 1); HSWZ(hv[2], hb, 2); HSWZ(hv[3], hb, 3);
        HSWZ(hv[4], hb, 4); HSWZ(hv[5], hb, 5); HSWZ(hv[6], hb, 6); HSWZ(hv[7], hb, 7);

        float a[4];
        #pragma unroll
        for (int g = 0; g < 4; ++g) {
            float acc = fmaf(xv.x, Wi0[g], bs[g]);
            acc = fmaf(xv.y, Wi1[g], acc);
            #pragma unroll
            for (int j = 0; j < 8; ++j) acc = fmaf(Wk[g][j], hv[j], acc);
            a[g] = acc;
        }
        const float ig = fast_sigmoid(a[0]);
        const float fg = fast_sigmoid(a[1]);
        const float gg = fast_tanh(a[2]);
        const float og = fast_sigmoid(a[3]);
        c = fmaf(fg, c, ig * gg);
        h = og * fast_tanh(c);

        hp[(s & 1) << 4] = (_Float16)h;            // kc = (s&1)*16 + dir*8 + j
        hp += (size_t)((s & 1) << 11);             // +2048 ele after odd steps
        xv = xv_n;
    }
}

// ---------------- Kernel 2: Wfc fp32 -> fp16, K-permutation + B-TILING ------
// Output tiled W2t[k/32][320][32] fp16 so the gemm's B-stage of one k-chunk is
// a single contiguous 20KB block (same bytes for every block -> lockstep L2
// hits), replacing 320 rows x 64B at 8832B stride. Value mapping unchanged:
// logical W2[n][p] with the d=1 time-reversal permutation. Coalesced writes.
__global__ __launch_bounds__(256) void conv_kernel(const float* __restrict__ Wfc,
                                                   _Float16* __restrict__ W2t)
{
    int i = blockIdx.x * 256 + threadIdx.x;        // destination index
    if (i < NPAD * KDIM) {
        int nk = i / BTILE_ELE;                    // k-tile index
        int r  = i - nk * BTILE_ELE;
        int n  = r >> 5;                           // 0..319 output row
        int kc = r & 31;
        int p  = nk * 32 + kc;                     // logical k
        _Float16 v = (_Float16)0.0f;
        if (n < NOUT) {
            int s = p >> 4, rr = p & 15;
            int src = (rr < 8) ? p : ((TSTEPS - 1 - s) * 16 + rr);
            v = (_Float16)Wfc[n * KDIM + src];
        }
        W2t[i] = v;
    }
}

// ---------------- Kernel 3: out[rows,276] = H[rows,4416] * W2t^T + bfc ------
// 3-deep counted-vmcnt pipeline, XOR-swizzled LDS. Both A (4KB) and B (20KB)
// chunk-stages are contiguous (tiled operands); stage addresses hoisted to
// running pointers (+4096 / +20480 bytes per chunk). LDS image identical to
// R2, so load_frags / cq swizzle / MFMA / epilogue untouched.
__global__ __launch_bounds__(256, 2) void gemm_kernel(
    const _Float16* __restrict__ H, const _Float16* __restrict__ W2,
    const float* __restrict__ bfc, float* __restrict__ out)
{
    __shared__ char smem[3][(GBM + GBN) * 64];     // per buf: A 4KB @0, B 20KB @4096

    const int tid  = threadIdx.x;
    const int lane = tid & 63;
    const int w    = tid >> 6;
    const int wm   = w >> 1;                       // 32-row half
    const int wn   = w & 1;                        // 160-col half
    const int m0   = blockIdx.x * GBM;
    const int l15  = lane & 15;
    const int l4   = lane >> 4;
    const int sel  = (l15 >> 1) & 3;               // row-derived swizzle selector
    const int cq   = (l4 ^ sel) << 4;              // swizzled 16B chunk offset in 64B row

    // base of this block's 64-row tile stripe in the tiled H layout
    const char* __restrict__ Htile = (const char*)(H + (size_t)(m0 >> 6) * ROWBLK_ELE);

    // ---- precomputed stage sources (rule #21: linear LDS dest, source holds
    // the involution; per-chunk advance is a constant byte stride) ----
    const int lrow = lane >> 2;                    // row within 1KB slot (16 rows x 64B)
    const int lc   = lane & 3;                     // 16B chunk within 64B row
    // A slot: j = w (<4), source row rA in [0,64)
    const int rA = (w << 4) | lrow;
    const char* pA = Htile + rA * 64 + ((lc ^ ((rA >> 1) & 3)) << 4);
    const int dA = w << 10;                        // wave-uniform LDS offset
    // B slots: j = w+4+4i, source row nr in [0,320)
    const char* pB[5];
    int dB[5];
    #pragma unroll
    for (int i = 0; i < 5; ++i) {
        const int j  = w + 4 + 4 * i;
        const int nr = ((j - 4) << 4) | lrow;
        pB[i] = (const char*)W2 + nr * 64 + ((lc ^ ((nr >> 1) & 3)) << 4);
        dB[i] = j << 10;
    }

    f32x4 acc[2][10] = {};

    auto stage = [&](int ck, char* buf) {
        async_copy16(pA + (size_t)ck * 4096, buf + dA);
        #pragma unroll
        for (int i = 0; i < 5; ++i)
            async_copy16(pB[i] + (size_t)ck * 20480, buf + dB[i]);
    };

    half8 af[2], bf[10];
    auto load_frags = [&](const char* buf) {
        const char* A  = buf;
        const char* Bb = buf + 4096;
        #pragma unroll
        for (int mi = 0; mi < 2; ++mi)
            af[mi] = *(const half8*)(A + (wm * 32 + mi * 16 + l15) * 64 + cq);
        #pragma unroll
        for (int ni = 0; ni < 10; ++ni)
            bf[ni] = *(const half8*)(Bb + (wn * 160 + ni * 16 + l15) * 64 + cq);
    };
    auto do_mfma = [&]() {
        #pragma unroll
        for (int ni = 0; ni < 10; ++ni) {
            #pragma unroll
            for (int mi = 0; mi < 2; ++mi)
                acc[mi][ni] = __builtin_amdgcn_mfma_f32_16x16x32_f16(af[mi], bf[ni], acc[mi][ni], 0, 0, 0);
        }
    };

    #define WAITVM(N) asm volatile("s_waitcnt vmcnt(" #N ")" ::: "memory")
    #define WAITLG()  asm volatile("s_waitcnt lgkmcnt(0)" ::: "memory")

    // prologue: fill the 3-deep pipe (18 loads in flight per wave)
    stage(0, smem[0]);
    stage(1, smem[1]);
    stage(2, smem[2]);

    #pragma unroll 1
    for (int ck = 0; ck < NCHUNK - 3; ck += 3) {
        #pragma unroll
        for (int u = 0; u < 3; ++u) {
            WAITVM(12);                            // my chunk (ck+u) loads done
            __builtin_amdgcn_s_barrier();          // everyone's chunk (ck+u) done
            load_frags(smem[u]);                   // 12x ds_read_b128 -> regs
            WAITLG();                              // reads committed before overwrite
            __builtin_amdgcn_s_barrier();          // all waves done reading buf u
            stage(ck + u + 3, smem[u]);            // refill with chunk ck+u+3
            __builtin_amdgcn_sched_barrier(0);     // keep stage issued before MFMAs
            do_mfma();                             // 20 MFMAs hide staging latency
        }
    }
    // tail: chunks 135,136,137 — drain 12 -> 6 -> 0
    WAITVM(12); __builtin_amdgcn_s_barrier(); load_frags(smem[0]); do_mfma();
    WAITVM(6);  __builtin_amdgcn_s_barrier(); load_frags(smem[1]); do_mfma();
    WAITVM(0);  __builtin_amdgcn_s_barrier(); load_frags(smem[2]); do_mfma();

    #undef WAITVM
    #undef WAITLG

    // C layout (16x16): col = lane&15, row = (lane>>4)*4 + reg
    #pragma unroll
    for (int ni = 0; ni < 10; ++ni) {
        const int n = wn * 160 + ni * 16 + l15;
        if (n < NOUT) {
            const float bv = bfc[n];
            #pragma unroll
            for (int mi = 0; mi < 2; ++mi) {
                const int mbase = m0 + wm * 32 + mi * 16 + l4 * 4;
                #pragma unroll
                for (int g = 0; g < 4; ++g)
                    out[(size_t)(mbase + g) * NOUT + n] = acc[mi][ni][g] + bv;
            }
        }
    }
}

extern "C" void kernel_launch(void* const* d_in, const int* in_sizes, int n_in,
                              void* d_out, int out_size, void* d_ws, size_t ws_size,
                              hipStream_t stream) {
    const float* x     = (const float*)d_in[0];
    const float* Wih_f = (const float*)d_in[1];
    const float* Whh_f = (const float*)d_in[2];
    const float* bih_f = (const float*)d_in[3];
    const float* bhh_f = (const float*)d_in[4];
    const float* Wih_b = (const float*)d_in[5];
    const float* Whh_b = (const float*)d_in[6];
    const float* bih_b = (const float*)d_in[7];
    const float* bhh_b = (const float*)d_in[8];
    const float* Wfc   = (const float*)d_in[9];
    const float* bfc   = (const float*)d_in[10];
    float* out = (float*)d_out;

    // Workspace layout: [W2t: NPAD*KDIM fp16][H chunk (tiled): chunk*KDIM fp16]
    _Float16* W2 = (_Float16*)d_ws;
    size_t h_off = ((size_t)NPAD * KDIM * 2 + 255) & ~(size_t)255;
    size_t avail = (ws_size > h_off) ? (ws_size - h_off) : 0;
    long maxrows = (long)(avail / ((size_t)KDIM * 2));
    int chunk = (int)((maxrows / 128) * 128);
    if (chunk > NBATCH) chunk = NBATCH;
    if (chunk < 128)    chunk = 128;
    _Float16* Hc = (_Float16*)((char*)d_ws + h_off);

    conv_kernel<<<(NPAD * KDIM + 255) / 256, 256, 0, stream>>>(Wfc, W2);

    for (int r0 = 0; r0 < NBATCH; r0 += chunk) {
        int rows = NBATCH - r0; if (rows > chunk) rows = chunk;
        lstm_kernel<<<rows / 16, 256, 0, stream>>>(x, Wih_f, Whh_f, bih_f, bhh_f,
                                                   Wih_b, Whh_b, bih_b, bhh_b,
                                                   r0, Hc);
        gemm_kernel<<<rows / 64, 256, 0, stream>>>(Hc, W2, bfc,
                                                   out + (size_t)r0 * NOUT);
    }
}